// Round 12
// baseline (412.609 us; speedup 1.0000x reference)
//
#include <hip/hip_runtime.h>
#include <stdint.h>

// Problem constants (fixed by reference: L=1024, B=8, D=2048)
#define L_SEQ 1024
#define BATCH 8
#define DIM   2048
#define GM    8192   // L*B
#define GN    6144   // 3*D
#define GK    2048   // D
#define SCALE_X 1.7320508075688772f  // sqrt(1 + 2*exp(0))

// GEMM geometry: 256x384 tile, 8 waves (2M x 4N), k-ring of 4 slices of 32
#define BM 256
#define BN 384
#define BKC 32

using bf16x8  = __attribute__((ext_vector_type(8))) __bf16;
using floatx4 = __attribute__((ext_vector_type(4))) float;

__device__ __forceinline__ unsigned short f2bf(float f) {
  unsigned u = __float_as_uint(f);
  u += 0x7FFFu + ((u >> 16) & 1u);   // round-to-nearest-even
  return (unsigned short)(u >> 16);
}
__device__ __forceinline__ float sigmoidf_fast(float z) {
  return __builtin_amdgcn_rcpf(1.0f + __expf(-z));
}
__device__ __forceinline__ void async16(const unsigned short* g, unsigned short* l) {
  __builtin_amdgcn_global_load_lds(
      (__attribute__((address_space(1))) unsigned int*)g,
      (__attribute__((address_space(3))) unsigned int*)l,
      16, 0, 0);
}

// ------------- fused prep: transpose-cast W -> Bt  +  cast x -> A (bf16) --------
// Blocks [0, 3072): 64x64 transpose tiles (n-tile = blk%96, k-tile = blk/96).
// Blocks [3072, 7168): grid-stride streaming cast of x.
// NEW Bt row permutation (U5 layout): W col n = 3d+j ->
//   np = (d>>6)*192 + (d&63)*3 + j  -- groups each 64-d chunk's {u0,u1,u2}
// into one 192-col band so ONE gemm block owns each scan region's lines.
__global__ __launch_bounds__(256) void prep_kernel(const float4* __restrict__ xin,
                                                   unsigned short* __restrict__ Aout,
                                                   const float* __restrict__ W,
                                                   unsigned short* __restrict__ Bt) {
  __shared__ float tile[64][65];
  const int blk = blockIdx.x;
  if (blk < 3072) {
    const int tx = threadIdx.x & 15, ty = threadIdx.x >> 4;
    const int n0 = (blk % 96) * 64;
    const int k0 = (blk / 96) * 64;
#pragma unroll
    for (int p = 0; p < 4; ++p) {
      const float4 v = *(const float4*)&W[(size_t)(k0 + ty + 16 * p) * GN + n0 + tx * 4];
      float* t = &tile[ty + 16 * p][tx * 4];
      t[0] = v.x; t[1] = v.y; t[2] = v.z; t[3] = v.w;
    }
    __syncthreads();
#pragma unroll
    for (int p = 0; p < 2; ++p) {
      const int jl = (threadIdx.x >> 3) + 32 * p;          // 0..63 n-local
      const int n = n0 + jl;
      const int dq = n / 3, j3 = n - 3 * dq;
      const int np = (dq >> 6) * 192 + (dq & 63) * 3 + j3;
      const int klb = (threadIdx.x & 7) * 8;               // 0..56 k-local
      union { unsigned short s[8]; uint4 q; } o;
#pragma unroll
      for (int kk = 0; kk < 8; ++kk) o.s[kk] = f2bf(tile[klb + kk][jl]);
      *(uint4*)&Bt[(size_t)np * GK + k0 + klb] = o.q;
    }
  } else {
    const int n4 = (GM * GK) / 4;
    for (int i = (blk - 3072) * 256 + threadIdx.x; i < n4; i += 4096 * 256) {
      float4 v = xin[i];
      union { unsigned short s[4]; unsigned long long ll; } o;
      o.s[0] = f2bf(v.x); o.s[1] = f2bf(v.y); o.s[2] = f2bf(v.z); o.s[3] = f2bf(v.w);
      *(unsigned long long*)&Aout[(size_t)i * 4] = o.ll;
    }
  }
}

// ---------------- GEMM: U5 <- A(GM x GK) * Bt(GN x GK)^T, bf16 out --------------
// Round-4 strict-alternation schedule (proven: 46.7% MfmaUtil, 0 conflicts),
// widened to 256x384 to amortize the fixed per-chunk cost (~2150 cyc of barrier/
// waitcnt/staging tax vs ~310 cyc MFMA issue at 256x256): 48 MFMA/wave/chunk,
// 512 blocks = 2 rounds/CU -> 128 chunk-instances/CU instead of 192.
// LDS = ring of 4 k-slices: 4*(16KB A + 24KB B) = 160 KB (full pool, 1 blk/CU).
// Per chunk c: WAITV(10) ; BAR0 ; R0(6 bF + 4 aF ds_read) + stageA(c+3, 2 loads)
// ; BAR1 ; lgkm0 ; 24 MFMA ; BAR2 ; R1(4 aF) + stageB(c+3, 3 loads) ; BAR3 ;
// lgkm0 ; 24 MFMA.  5 loads/thread/chunk; entry outstanding = 15, WAITV(10)
// seals slot c (issued 3 chunks ~7000 cyc earlier -> free). Tail 10/5/0.
// LDS swizzle: identical to prior rounds (read-side XOR, inverse-permuted
// global source, lane-linear LDS dest). K-order ascending -> bit-identical.
// Epilogue: writes the U5 scan layout: row (b,dc,l) = 192 shorts {u0,u1,u2}x64;
// whole (b,dc) region written by THIS block only (single-writer lines).
// XCD swizzle: 512 = 8 XCD x 2 rounds x 32 slots (4y x 8x rectangles).

#define WAITV(N) asm volatile("s_waitcnt vmcnt(" #N ")" ::: "memory")
#define LGKM0 asm volatile("s_waitcnt lgkmcnt(0)" ::: "memory"); \
              __builtin_amdgcn_sched_barrier(0)

#define CHUNK(cexpr, SL, DOSTAGE)                                             \
  {                                                                           \
    __builtin_amdgcn_s_barrier();  /* BAR0 */                                 \
    __builtin_amdgcn_sched_barrier(0);                                        \
    const int c_ = (cexpr);                                                   \
    const char* aB_ = AsB + (SL) * 16384;                                     \
    const char* bB_ = BsB + (SL) * 24576;                                     \
    bf16x8 bF[6], aF[4];                                                      \
    _Pragma("unroll") for (int nt = 0; nt < 6; ++nt)                          \
        bF[nt] = *(const bf16x8*)(bB_ + SB0 + nt * 1024);                     \
    _Pragma("unroll") for (int mt = 0; mt < 4; ++mt)                          \
        aF[mt] = *(const bf16x8*)(aB_ + SA0 + mt * 1024);                     \
    if (DOSTAGE) {                                                            \
      unsigned short* ad_ = (unsigned short*)(AsL + ((c_ + 3) & 3) * 16384);  \
      const int ko_ = (c_ + 3) * BKC;                                         \
      async16(aG0 + ko_, ad_ + (size_t)tid * 8);                              \
      async16(aG1 + ko_, ad_ + (size_t)(tid + 512) * 8);                      \
    }                                                                         \
    __builtin_amdgcn_sched_barrier(0);                                        \
    __builtin_amdgcn_s_barrier();  /* BAR1: read-burst | MFMA-burst fence */  \
    LGKM0;                                                                    \
    __builtin_amdgcn_s_setprio(1);                                            \
    _Pragma("unroll") for (int mt = 0; mt < 4; ++mt)                          \
      _Pragma("unroll") for (int nt = 0; nt < 6; ++nt)                        \
        acc[mt][nt] = __builtin_amdgcn_mfma_f32_16x16x32_bf16(                \
            aF[mt], bF[nt], acc[mt][nt], 0, 0, 0);                            \
    __builtin_amdgcn_s_setprio(0);                                            \
    __builtin_amdgcn_sched_barrier(0);                                        \
    __builtin_amdgcn_s_barrier();  /* BAR2 */                                 \
    _Pragma("unroll") for (int mt = 0; mt < 4; ++mt)                          \
        aF[mt] = *(const bf16x8*)(aB_ + SA0 + 4096 + mt * 1024);              \
    if (DOSTAGE) {                                                            \
      unsigned short* bd_ = (unsigned short*)(BsL + ((c_ + 3) & 3) * 24576);  \
      const int ko_ = (c_ + 3) * BKC;                                        \
      async16(bG0 + ko_, bd_ + (size_t)tid * 8);                              \
      async16(bG1 + ko_, bd_ + (size_t)(tid + 512) * 8);                      \
      async16(bG2 + ko_, bd_ + (size_t)(tid + 1024) * 8);                     \
    }                                                                         \
    __builtin_amdgcn_sched_barrier(0);                                        \
    __builtin_amdgcn_s_barrier();  /* BAR3 */                                 \
    LGKM0;                                                                    \
    __builtin_amdgcn_s_setprio(1);                                            \
    _Pragma("unroll") for (int mt = 0; mt < 4; ++mt)                          \
      _Pragma("unroll") for (int nt = 0; nt < 6; ++nt)                        \
        acc[mt + 4][nt] = __builtin_amdgcn_mfma_f32_16x16x32_bf16(            \
            aF[mt], bF[nt], acc[mt + 4][nt], 0, 0, 0);                        \
    __builtin_amdgcn_s_setprio(0);                                            \
    __builtin_amdgcn_sched_barrier(0);                                        \
  }

__global__ __launch_bounds__(512) void gemm_kernel(const unsigned short* __restrict__ A,
                                                   const unsigned short* __restrict__ Bt,
                                                   unsigned short* __restrict__ U5) {
  __shared__ alignas(16) unsigned short As[4][BM * BKC];  // 64 KB
  __shared__ alignas(16) unsigned short Bs[4][BN * BKC];  // 96 KB (160 total)
  const int tid  = threadIdx.x;
  const int wave = tid >> 6, lane = tid & 63;
  const int quad = lane >> 4, lrow = lane & 15;
  const int wm = (wave >> 2) * 128;  // 2 M-waves
  const int wn = (wave & 3) * 96;    // 4 N-waves x 96 cols

  // XCD swizzle: 512 blocks = 8 XCD x 2 rounds x 32 slots (4y x 8x rectangles)
  const int f    = blockIdx.y * (GN / BN) + blockIdx.x;
  const int xcd  = f & 7;
  const int slot = f >> 3;
  const int rnd  = slot >> 5;        // 0..1
  const int ss   = slot & 31;        // 0..31
  const int mBase = (4 * xcd + (ss & 3)) * BM;   // y-tile 0..31
  const int nBase = (8 * rnd + (ss >> 2)) * BN;  // x-tile 0..15

  floatx4 acc[8][6] = {};

  // staging: A slots L = tid, tid+512 (1024 x 16B); B slots L = tid, +512, +1024
  // (1536 x 16B). Lane-linear LDS dest; inverse swizzle on global source.
  int rA_[2], sA_[2], rB_[3], sB_[3];
#pragma unroll
  for (int j = 0; j < 2; ++j) {
    const int Lj = tid + j * 512;
    const int p = Lj >> 3, w = Lj & 7, v = w ^ (p & 7);
    rA_[j] = 2 * p + (v >> 2); sA_[j] = v & 3;
  }
#pragma unroll
  for (int j = 0; j < 3; ++j) {
    const int Lj = tid + j * 512;
    const int p = Lj >> 3, w = Lj & 7, v = w ^ (p & 7);
    rB_[j] = 2 * p + (v >> 2); sB_[j] = v & 3;
  }
  const unsigned short* aG0 = A  + (size_t)(mBase + rA_[0]) * GK + sA_[0] * 8;
  const unsigned short* aG1 = A  + (size_t)(mBase + rA_[1]) * GK + sA_[1] * 8;
  const unsigned short* bG0 = Bt + (size_t)(nBase + rB_[0]) * GK + sB_[0] * 8;
  const unsigned short* bG1 = Bt + (size_t)(nBase + rB_[1]) * GK + sB_[1] * 8;
  const unsigned short* bG2 = Bt + (size_t)(nBase + rB_[2]) * GK + sB_[2] * 8;

  // ds_read byte offsets within a slice (+16 rows = +1024 B)
  const int rA = wm + lrow;
  const int SA0 = (rA >> 1) * 128 + ((((rA & 1) * 4 + quad) ^ ((rA >> 1) & 7)) * 16);
  const int rB = wn + lrow;
  const int SB0 = (rB >> 1) * 128 + ((((rB & 1) * 4 + quad) ^ ((rB >> 1) & 7)) * 16);
  const char* AsB = (const char*)As;
  const char* BsB = (const char*)Bs;
  char* AsL = (char*)As;
  char* BsL = (char*)Bs;

  // prologue: stage chunks 0,1,2 (15 loads/thread in flight; A then B per slot)
#pragma unroll
  for (int c = 0; c < 3; ++c) {
    unsigned short* ad = (unsigned short*)(AsL + c * 16384);
    unsigned short* bd = (unsigned short*)(BsL + c * 24576);
    async16(aG0 + c * BKC, ad + (size_t)tid * 8);
    async16(aG1 + c * BKC, ad + (size_t)(tid + 512) * 8);
    async16(bG0 + c * BKC, bd + (size_t)tid * 8);
    async16(bG1 + c * BKC, bd + (size_t)(tid + 512) * 8);
    async16(bG2 + c * BKC, bd + (size_t)(tid + 1024) * 8);
  }

  // main loop: chunks 0..59 (stage c+3), then peeled 60..63
#pragma unroll 1
  for (int cc = 0; cc < 15; ++cc) {
    const int cb = cc * 4;
#pragma unroll
    for (int j = 0; j < 4; ++j) {
      WAITV(10);
      CHUNK(cb + j, j, true);
    }
  }
  WAITV(10); CHUNK(60, 0, true);   // stages chunk 63
  WAITV(10); CHUNK(61, 1, false);
  WAITV(5);  CHUNK(62, 2, false);
  WAITV(0);  CHUNK(63, 3, false);

  // Epilogue -> U5: row (b, dc, l) = 192 shorts; gn is already np-space.
  // C/D: col = lane&15 (N), row = quad*4 + reg (M). gm 4-aligned: l = gm>>3
  // fixed across q; b = (gm&7) + q.
#pragma unroll
  for (int mt = 0; mt < 8; ++mt) {
    const int gm = mBase + wm + mt * 16 + quad * 4;
    const int l = gm >> 3;
    const int b0 = gm & 7;
#pragma unroll
    for (int nt = 0; nt < 6; ++nt) {
      const int gn = nBase + wn + nt * 16 + lrow;
      const int dc = gn / 192, tc = gn - dc * 192;
      unsigned short* base = U5 + ((size_t)(b0 * 32 + dc) * 1024 + l) * 192 + tc;
#pragma unroll
      for (int q = 0; q < 4; ++q)
        base[(size_t)q * 32 * 1024 * 192] = f2bf(acc[mt][nt][q]);
    }
  }
}

// ------------- SRU scan over U5: contiguous staging, producer/consumer ----------
// 256 blocks x 128 threads. Block (b,dch): u-stream = U5 region (b*32+dch),
// 384 B/step CONTIGUOUS -> each 16-step slot staged with 6x 1-KB contiguous
// global_load_lds (gemm-class address pattern; the scattered-128B pattern was
// the delivery bottleneck). x staged from A_bf as before (2 instr/slot).
// Ring: 8 slots x 8 KB (6 KB u + 2 KB x) = 64 KB; distance 6 (48 loads in
// flight <= 63 cap). WAITV(40) seals slot p+1 each phase; tail 32/24/16/8/0.
// Consumer: per step u0,u1,u2 at sp[s*192+lane*3 +0/1/2], x at sp[3072+s*64+
// lane]; identical math/order -> bit-identical output.
__global__ __launch_bounds__(128) void sru_scan_u5(const unsigned short* __restrict__ U5,
                                                   const unsigned short* __restrict__ xbf,
                                                   const float* __restrict__ c0,
                                                   const float* __restrict__ wc,
                                                   const float* __restrict__ bias,
                                                   float* __restrict__ out) {
  __shared__ alignas(16) unsigned short Sm[8][4096];  // 8 slots x 8 KB
  const int tid  = threadIdx.x;
  const int wave = tid >> 6, lane = tid & 63;
  const int blk = blockIdx.x;
  const int b = blk >> 5, dch = blk & 31;
  const int d0 = dch * 64;

  constexpr size_t XSs = (size_t)BATCH * DIM;  // shorts per l-step (x)
  constexpr int XS = BATCH * DIM;              // floats per l-step (out)

  const unsigned short* ub = U5 + (size_t)(b * 32 + dch) * 1024 * 192;

  if (wave == 1) {
    // ---------------- producer ----------------
    const int s8 = lane >> 3, c8 = lane & 7;
    const unsigned short* xg = xbf + (size_t)b * DIM + d0 + c8 * 8 + (size_t)s8 * XSs;

#define STAGE_SLOT(SL, L0S)                                                   \
    {                                                                         \
      unsigned short* dst = &Sm[(SL)][0] + lane * 8;                          \
      const size_t base_ = (size_t)(L0S) * 192;                               \
      async16(ub + base_ + 0 * 512 + lane * 8 - lane * 8 + lane * 8, dst);    \
      async16(ub + base_ + 1 * 512 + lane * 8, dst + 512);                    \
      async16(ub + base_ + 2 * 512 + lane * 8, dst + 1024);                   \
      async16(ub + base_ + 3 * 512 + lane * 8, dst + 1536);                   \
      async16(ub + base_ + 4 * 512 + lane * 8, dst + 2048);                   \
      async16(ub + base_ + 5 * 512 + lane * 8, dst + 2560);                   \
      async16(xg + (size_t)(L0S) * XSs, dst + 3072);                          \
      async16(xg + (size_t)((L0S) + 8) * XSs, dst + 3584);                    \
    }

    // prologue: slots 0..5 (48 loads); seal slot 0
#pragma unroll 1
    for (int q = 0; q < 6; ++q) STAGE_SLOT(q, 16 * q);
    WAITV(40);
#pragma unroll 1
    for (int p = 0; p < 64; ++p) {
      __builtin_amdgcn_s_barrier();
      __builtin_amdgcn_sched_barrier(0);
      if (p < 58)      { STAGE_SLOT((p + 6) & 7, 16 * (p + 6)); WAITV(40); }
      else if (p == 58) WAITV(32);
      else if (p == 59) WAITV(24);
      else if (p == 60) WAITV(16);
      else if (p == 61) WAITV(8);
      else if (p == 62) WAITV(0);
      __builtin_amdgcn_sched_barrier(0);
    }
#undef STAGE_SLOT
  } else {
    // ---------------- consumer ----------------
    const int d = d0 + lane;
    const int e = b * DIM + d;
    const float vf = wc[d], vr = wc[DIM + d];
    const float bfv = bias[d], brv = bias[DIM + d];
    float c = c0[e];
    float* hp = out + (size_t)b * DIM + d;

#pragma unroll 1
    for (int p = 0; p < 64; ++p) {
      __builtin_amdgcn_s_barrier();
      __builtin_amdgcn_sched_barrier(0);
      const unsigned short* sp = &Sm[p & 7][0];
#pragma unroll
      for (int s = 0; s < 16; ++s) {
        const unsigned u0v = sp[s * 192 + lane * 3];
        const unsigned u1v = sp[s * 192 + lane * 3 + 1];
        const unsigned u2v = sp[s * 192 + lane * 3 + 2];
        const unsigned xv  = sp[3072 + s * 64 + lane];
        const float a0 = __uint_as_float(u0v << 16);
        const float u1 = __uint_as_float(u1v << 16);
        const float u2 = __uint_as_float(u2v << 16);
        const float ax = __uint_as_float(xv << 16) * SCALE_X;
        const float fg = sigmoidf_fast(u1 + fmaf(vf, c, bfv));
        c = fmaf(c - a0, fg, a0);
        const float rr = sigmoidf_fast(u2 + fmaf(vr, c, brv));
        __builtin_nontemporal_store(fmaf(rr, c - ax, ax), hp);
        hp += XS;
      }
      LGKM0;  // all slot reads complete before passing the next barrier
    }
    out[(size_t)L_SEQ * XS + e] = c;
  }
}

// --------------------------------- launcher ------------------------------------
extern "C" void kernel_launch(void* const* d_in, const int* in_sizes, int n_in,
                              void* d_out, int out_size, void* d_ws, size_t ws_size,
                              hipStream_t stream) {
  const float* x    = (const float*)d_in[0];
  const float* c0   = (const float*)d_in[1];
  const float* W    = (const float*)d_in[2];
  const float* wc   = (const float*)d_in[3];
  const float* bias = (const float*)d_in[4];
  float* out = (float*)d_out;

  char* ws = (char*)d_ws;
  // layout: A 33,554,432 (+512K pad) | Bt 25,165,824 | U5 100,663,296 (+pad)
  unsigned short* A_bf  = (unsigned short*)(ws);
  unsigned short* Bt_bf = (unsigned short*)(ws + 34078720);
  unsigned short* U5_s  = (unsigned short*)(ws + 59244544);

  prep_kernel<<<7168, 256, 0, stream>>>((const float4*)x, A_bf, W, Bt_bf);
  gemm_kernel<<<dim3(GN / BN, GM / BM), 512, 0, stream>>>(A_bf, Bt_bf, U5_s);
  sru_scan_u5<<<256, 128, 0, stream>>>(U5_s, A_bf, c0, wc, bias, out);
}